// Round 19
// baseline (357.745 us; speedup 1.0000x reference)
//
#include <hip/hip_runtime.h>
#include <hip/hip_bf16.h>
#include <math.h>

typedef unsigned short u16;
typedef unsigned int   u32;
typedef __attribute__((ext_vector_type(8))) short bf16x8;
typedef __attribute__((ext_vector_type(4))) float f32x4;

#define L_LEAF 131072
#define N_ALL  262143
#define HST 136   // h/c LDS row stride (elems): 128 + 8

// global row offset of tree level L (L=0 leaves): OFF = sum_{j<L} 131072>>j
#define OFFL(L) (262144 - (262144 >> (L)))

__device__ __forceinline__ float b2f(u16 u) {
    u32 x = ((u32)u) << 16;
    return __builtin_bit_cast(float, x);
}
__device__ __forceinline__ float lo2f(u32 p) { u32 x = p << 16;          return __builtin_bit_cast(float, x); }
__device__ __forceinline__ float hi2f(u32 p) { u32 x = p & 0xffff0000u;  return __builtin_bit_cast(float, x); }
__device__ __forceinline__ u16 f2b(float f) {
    u32 x = __builtin_bit_cast(u32, f);
    u32 r = x + 0x7fffu + ((x >> 16) & 1u);
    return (u16)(r >> 16);
}
__device__ __forceinline__ u32 pack2(float a, float b) {
    return (u32)f2b(a) | ((u32)f2b(b) << 16);
}
__device__ __forceinline__ float fsigm(float x) {
    return __builtin_amdgcn_rcpf(1.f + __builtin_amdgcn_exp2f(x * -1.44269504f));
}
__device__ __forceinline__ float ftanh(float x) {
    return 1.f - 2.f * __builtin_amdgcn_rcpf(__builtin_amdgcn_exp2f(x * 2.88539008f) + 1.f);
}

// ---------------------------------------------------------------------------
// proj of n_rows rows held in LDS Hrows[row*HST + d] -> out[grow0+row][3]
// ---------------------------------------------------------------------------
__device__ __forceinline__ void proj_rows(
    const u16* Hrows, int n_rows, const float* pwl4, const float* pbl,
    float* __restrict__ out, int grow0, int tid)
{
    int rp = tid >> 2, p = tid & 3;
    if (rp < n_rows) {
        float hv[32];
        #pragma unroll
        for (int c = 0; c < 4; ++c) {
            bf16x8 v = *(const bf16x8*)&Hrows[rp * HST + p * 32 + c * 8];
            #pragma unroll
            for (int e = 0; e < 8; ++e) hv[c * 8 + e] = b2f((u16)v[e]);
        }
        #pragma unroll
        for (int j = 0; j < 3; ++j) {
            float s = 0.f;
            #pragma unroll
            for (int e = 0; e < 32; ++e)
                s = fmaf(hv[e], pwl4[p * 100 + j * 32 + e], s);
            s += __shfl_xor(s, 1);
            s += __shfl_xor(s, 2);
            if (p == 0) out[(size_t)(grow0 + rp) * 3 + j] = s + pbl[j];
        }
    }
}

__device__ __forceinline__ void stage_pw(
    const float* __restrict__ proj_w, const float* __restrict__ proj_b,
    float* pwl4, float* pbl, int tid, int nthreads)
{
    for (int idx = tid; idx < 384; idx += nthreads) {
        int j = idx >> 7, d = idx & 127;
        int p = d >> 5, e = d & 31;
        pwl4[p * 100 + j * 32 + e] = proj_w[idx];
    }
    if (tid < 3) pbl[tid] = proj_b[tid];
}

// ---------------------------------------------------------------------------
// 512-thread (8-wave) tree level, SINGLE combined pass: wave wv owns 16 cols
// (d0 = wv*16+lm), one nt per gate (nt = gbase + wv).
// ---------------------------------------------------------------------------
template<int MTN>
__device__ __forceinline__ void tree_level8(
    const bf16x8* __restrict__ BpkT, u16* HA, u16* CA,
    float tbi, float tbo, float tbu, float fb1, float fb2,
    int n_out, int ro, int wv, int l, int lm, int lk, int d0)
{
    f32x4 ai[MTN], ao_[MTN], au[MTN], a1[MTN], a2[MTN];
    #pragma unroll
    for (int mt = 0; mt < MTN; ++mt) {
        ai[mt] = (f32x4){0.f, 0.f, 0.f, 0.f};
        ao_[mt] = ai[mt]; au[mt] = ai[mt]; a1[mt] = ai[mt]; a2[mt] = ai[mt];
    }
    #pragma unroll
    for (int kc = 0; kc < 8; ++kc) {
        int k0 = kc * 32 + lk * 8;
        bf16x8 a[MTN];
        #pragma unroll
        for (int mt = 0; mt < MTN; ++mt) {
            int rr = ro + mt * 16 + lm;
            const u16* src = (k0 < 128) ? &HA[(2 * rr) * HST + k0]
                                        : &HA[(2 * rr + 1) * HST + (k0 - 128)];
            a[mt] = *(const bf16x8*)src;
        }
        bf16x8 bi = BpkT[(kc * 40 + 0  + wv) * 64 + l];
        bf16x8 bo = BpkT[(kc * 40 + 8  + wv) * 64 + l];
        bf16x8 bu = BpkT[(kc * 40 + 16 + wv) * 64 + l];
        bf16x8 b1 = BpkT[(kc * 40 + 24 + wv) * 64 + l];
        bf16x8 b2 = BpkT[(kc * 40 + 32 + wv) * 64 + l];
        #pragma unroll
        for (int mt = 0; mt < MTN; ++mt) {
            ai[mt]  = __builtin_amdgcn_mfma_f32_16x16x32_bf16(a[mt], bi, ai[mt], 0, 0, 0);
            ao_[mt] = __builtin_amdgcn_mfma_f32_16x16x32_bf16(a[mt], bo, ao_[mt], 0, 0, 0);
            au[mt]  = __builtin_amdgcn_mfma_f32_16x16x32_bf16(a[mt], bu, au[mt], 0, 0, 0);
            a1[mt]  = __builtin_amdgcn_mfma_f32_16x16x32_bf16(a[mt], b1, a1[mt], 0, 0, 0);
            a2[mt]  = __builtin_amdgcn_mfma_f32_16x16x32_bf16(a[mt], b2, a2[mt], 0, 0, 0);
        }
    }

    float cv[MTN][4], hv[MTN][4];
    #pragma unroll
    for (int mt = 0; mt < MTN; ++mt)
        #pragma unroll
        for (int r = 0; r < 4; ++r) {
            int row = ro + mt * 16 + lk * 4 + r;
            float lc = b2f(CA[(2 * row) * HST + d0]);
            float rc = b2f(CA[(2 * row + 1) * HST + d0]);
            float ivv = fsigm(ai[mt][r] + tbi);
            float uv  = fmaxf(au[mt][r] + tbu, 0.f);
            float f1  = fsigm(a1[mt][r] + fb1);
            float f2  = fsigm(a2[mt][r] + fb2);
            float c_  = ivv * uv + f1 * lc + f2 * rc;
            cv[mt][r] = c_;
            hv[mt][r] = fsigm(ao_[mt][r] + tbo) * fmaxf(c_, 0.f);
        }

    __syncthreads();
    #pragma unroll
    for (int mt = 0; mt < MTN; ++mt)
        #pragma unroll
        for (int r = 0; r < 4; ++r) {
            int row = ro + mt * 16 + lk * 4 + r;
            if (row < n_out) {
                HA[row * HST + d0] = f2b(hv[mt][r]);
                CA[row * HST + d0] = f2b(cv[mt][r]);
            }
        }
    __syncthreads();
}

// ---------------------------------------------------------------------------
// K_pre (2022 blocks, 256t): xz (0..49), BpkL (50..109), BpkT (110..189),
// emb f32->bf16 (190..2021). No LSTM here (moved to k_fused block 0).
// ---------------------------------------------------------------------------
__global__ __launch_bounds__(256) void k_pre(
    const float* __restrict__ Wi_w, const float* __restrict__ Wo_w,
    const float* __restrict__ Wu_w,
    const float* __restrict__ Ui_w, const float* __restrict__ Uo_w,
    const float* __restrict__ Uu_w, const float* __restrict__ Uf1_w,
    const float* __restrict__ Uf2_w,
    const float* __restrict__ emb, const float* __restrict__ wih,
    const float* __restrict__ bih, const float* __restrict__ bhh,
    const int* __restrict__ targets,
    u16* __restrict__ BpkL, u16* __restrict__ BpkT, float* __restrict__ xz,
    u16* __restrict__ emb_bf)
{
    __shared__ float te[300];
    const int b = blockIdx.x, tid = threadIdx.x;

    if (b < 50) {
        int t = b;
        int tgt = targets[t];
        if (tid < 75) {
            float4 v = *(const float4*)(emb + (size_t)tgt * 300 + tid * 4);
            te[tid * 4 + 0] = v.x; te[tid * 4 + 1] = v.y;
            te[tid * 4 + 2] = v.z; te[tid * 4 + 3] = v.w;
        }
        __syncthreads();
        for (int rep = 0; rep < 2; ++rep) {
            int j = tid + rep * 256;
            float acc = bih[j] + bhh[j];
            const float* wr = wih + (size_t)j * 300;
            for (int k4 = 0; k4 < 75; ++k4) {
                float4 wv = *(const float4*)(wr + k4 * 4);
                float4 tv = *(const float4*)&te[k4 * 4];
                acc = fmaf(wv.x, tv.x, acc);
                acc = fmaf(wv.y, tv.y, acc);
                acc = fmaf(wv.z, tv.z, acc);
                acc = fmaf(wv.w, tv.w, acc);
            }
            xz[t * 512 + j] = acc;
        }
    } else if (b < 110) {
        int gid = (b - 50) * 256 + tid;
        if (gid >= 15360) return;
        int l  = gid & 63;
        int nt = (gid >> 6) % 24;
        int kc = gid / (24 * 64);
        int n  = nt * 16 + (l & 15);
        int g  = n >> 7, d = n & 127;
        int k0 = kc * 32 + (l >> 4) * 8;
        const float* W = (g == 0) ? Wi_w : (g == 1) ? Wo_w : Wu_w;
        #pragma unroll
        for (int j = 0; j < 8; ++j) {
            int k = k0 + j;
            float v = (k < 300) ? W[d * 300 + k] : 0.f;
            BpkL[(size_t)gid * 8 + j] = f2b(v);
        }
    } else if (b < 190) {
        int gid = (b - 110) * 256 + tid;
        if (gid >= 20480) return;
        int l  = gid & 63;
        int nt = (gid >> 6) % 40;
        int kc = gid / (40 * 64);
        int n  = nt * 16 + (l & 15);
        int g  = n >> 7, d = n & 127;
        int k0 = kc * 32 + (l >> 4) * 8;
        #pragma unroll
        for (int j = 0; j < 8; ++j) {
            int k = k0 + j;
            float v;
            if (g == 0)      v = Ui_w[d * 384 + k];
            else if (g == 1) v = Uo_w[d * 384 + k];
            else if (g == 2) v = Uu_w[d * 384 + k];
            else if (g == 3) v = (k < 128)  ? Uf1_w[d * 128 + k]       : 0.f;
            else             v = (k >= 128) ? Uf2_w[d * 128 + (k-128)] : 0.f;
            BpkT[(size_t)gid * 8 + j] = f2b(v);
        }
    } else {
        int base = (b - 190) * 2048;
        #pragma unroll
        for (int it = 0; it < 8; ++it) {
            int idx = base + it * 256 + tid;
            if (idx < 3750000) {
                float4 v = *(const float4*)(emb + (size_t)idx * 4);
                ushort4 o;
                o.x = f2b(v.x); o.y = f2b(v.y); o.z = f2b(v.z); o.w = f2b(v.w);
                *(ushort4*)(emb_bf + (size_t)idx * 4) = o;
            }
        }
    }
}

// ---------------------------------------------------------------------------
// K_fused (2049 blocks, 512t):
//  block 0: LSTM scan (K-split-8, 512 threads) -> tb, sets flag.
//  blocks 1..2048: leaf GEMM (A direct from emb_bf) + leaf proj; then spin
//  on flag (need tb) and run tree levels 1-2 + proj + level-2 h/c write.
// ---------------------------------------------------------------------------
__global__ __launch_bounds__(512) void k_fused(
    const u16* __restrict__ emb_bf, const int* __restrict__ toks,
    const bf16x8* __restrict__ BpkL, const bf16x8* __restrict__ BpkT,
    const float* __restrict__ Wi_b, const float* __restrict__ Wo_b, const float* __restrict__ Wu_b,
    const float* __restrict__ Uf1_b, const float* __restrict__ Uf2_b,
    u16* __restrict__ h_all, u16* __restrict__ c_all,
    const float* __restrict__ proj_w, const float* __restrict__ proj_b,
    float* __restrict__ out,
    const float* __restrict__ whh, const float* __restrict__ xz,
    const float* __restrict__ Ui_w, const float* __restrict__ Uo_w,
    const float* __restrict__ Uu_w,
    const float* __restrict__ Ui_b, const float* __restrict__ Uo_b,
    const float* __restrict__ Uu_b,
    float* __restrict__ tb, int* __restrict__ flag)
{
    __shared__ __align__(16) u16 Hs[64 * HST];   // 17,408 B
    __shared__ __align__(16) u16 Cs[64 * HST];   // 17,408 B
    __shared__ float pwl4[400];
    __shared__ float pbl[3];
    const int tid = threadIdx.x;

    if (blockIdx.x == 0) {
        // ------------- LSTM: 512 threads, K-split-8 (wreg[8][8] = 64 VGPR) ----
        float* hbuf = (float*)Hs;            // [128]
        float* zp   = (float*)Cs;            // [8][512] = 16,384 B <= 17,408 B
        const int q = tid & 7, rg = tid >> 3;   // rg in [0,64)

        u32 wreg[8][8];
        #pragma unroll
        for (int i = 0; i < 8; ++i) {
            const float* wr = whh + (size_t)(rg * 8 + i) * 128 + q * 16;
            #pragma unroll
            for (int k2 = 0; k2 < 8; ++k2)
                wreg[i][k2] = pack2(wr[2 * k2], wr[2 * k2 + 1]);
        }
        float c0 = 0.f;
        float nx0 = 0.f, nx1 = 0.f, nx2 = 0.f, nx3 = 0.f;
        if (tid < 128) {
            hbuf[tid] = 0.f;
            nx0 = xz[tid];       nx1 = xz[128 + tid];
            nx2 = xz[256 + tid]; nx3 = xz[384 + tid];
        }
        __syncthreads();

        for (int t = 0; t < 50; ++t) {
            float4 hv[4];
            #pragma unroll
            for (int m = 0; m < 4; ++m) hv[m] = ((const float4*)hbuf)[q * 4 + m];
            float za[8];
            #pragma unroll
            for (int i = 0; i < 8; ++i) {
                float a = 0.f;
                #pragma unroll
                for (int m = 0; m < 4; ++m) {
                    u32 w0 = wreg[i][2 * m], w1 = wreg[i][2 * m + 1];
                    a = fmaf(lo2f(w0), hv[m].x, a);
                    a = fmaf(hi2f(w0), hv[m].y, a);
                    a = fmaf(lo2f(w1), hv[m].z, a);
                    a = fmaf(hi2f(w1), hv[m].w, a);
                }
                za[i] = a;
            }
            float* zr = zp + q * 512 + rg * 8;
            *(float4*)zr       = (float4){za[0], za[1], za[2], za[3]};
            *(float4*)(zr + 4) = (float4){za[4], za[5], za[6], za[7]};
            __syncthreads();
            if (tid < 128) {
                int d = tid;
                float zi = nx0, zf = nx1, zg = nx2, zo = nx3;
                #pragma unroll
                for (int qq = 0; qq < 8; ++qq) {
                    zi += zp[qq * 512 + d];
                    zf += zp[qq * 512 + 128 + d];
                    zg += zp[qq * 512 + 256 + d];
                    zo += zp[qq * 512 + 384 + d];
                }
                if (t < 49) {
                    const float* xn = xz + (t + 1) * 512;
                    nx0 = xn[d]; nx1 = xn[128 + d]; nx2 = xn[256 + d]; nx3 = xn[384 + d];
                }
                c0 = fsigm(zf) * c0 + fsigm(zi) * ftanh(zg);
                hbuf[d] = fsigm(zo) * ftanh(c0);
            }
            __syncthreads();
        }

        if (tid < 384) {
            int g = tid >> 7, dd = tid & 127;
            const float* W = (g == 0) ? Ui_w : (g == 1) ? Uo_w : Uu_w;
            const float* B = (g == 0) ? Ui_b : (g == 1) ? Uo_b : Uu_b;
            float acc = B[dd];
            for (int k = 0; k < 128; ++k)
                acc = fmaf(W[dd * 384 + 256 + k], hbuf[k], acc);
            tb[tid] = acc;
        }
        __threadfence();
        __syncthreads();
        if (tid == 0) atomicExch(flag, 1);
        return;
    }

    // ------------- leaf path (blocks 1..2048) -------------
    const int b = blockIdx.x - 1;

    stage_pw(proj_w, proj_b, pwl4, pbl, tid, 512);

    const int wv = tid >> 6, l = tid & 63;
    const int lm = l & 15, lk = l >> 4;
    const int d0 = wv * 16 + lm;

    const float bi_ = Wi_b[d0], bo_ = Wo_b[d0], bu_ = Wu_b[d0];
    const float fb1 = Uf1_b[d0], fb2 = Uf2_b[d0];

    const u16* arow[4];
    #pragma unroll
    for (int mt = 0; mt < 4; ++mt) {
        int tok = toks[b * 64 + mt * 16 + lm];
        arow[mt] = emb_bf + (size_t)tok * 300 + lk * 8;
    }

    f32x4 ai[4], ao_[4], au[4];
    #pragma unroll
    for (int mt = 0; mt < 4; ++mt) {
        ai[mt] = (f32x4){0.f, 0.f, 0.f, 0.f};
        ao_[mt] = ai[mt]; au[mt] = ai[mt];
    }
    #pragma unroll
    for (int kc = 0; kc < 10; ++kc) {
        bf16x8 a[4];
        #pragma unroll
        for (int mt = 0; mt < 4; ++mt)
            a[mt] = *(const bf16x8*)(arow[mt] + kc * 32);
        bf16x8 bi = BpkL[(kc * 24 + 0  + wv) * 64 + l];
        bf16x8 bo = BpkL[(kc * 24 + 8  + wv) * 64 + l];
        bf16x8 bu = BpkL[(kc * 24 + 16 + wv) * 64 + l];
        #pragma unroll
        for (int mt = 0; mt < 4; ++mt) {
            ai[mt]  = __builtin_amdgcn_mfma_f32_16x16x32_bf16(a[mt], bi, ai[mt], 0, 0, 0);
            ao_[mt] = __builtin_amdgcn_mfma_f32_16x16x32_bf16(a[mt], bo, ao_[mt], 0, 0, 0);
            au[mt]  = __builtin_amdgcn_mfma_f32_16x16x32_bf16(a[mt], bu, au[mt], 0, 0, 0);
        }
    }

    float cv[4][4], hvv[4][4];
    #pragma unroll
    for (int mt = 0; mt < 4; ++mt)
        #pragma unroll
        for (int r = 0; r < 4; ++r) {
            float ivv = fsigm(ai[mt][r] + bi_);
            float uv  = fmaxf(au[mt][r] + bu_, 0.f);
            float c_  = ivv * uv;
            cv[mt][r] = c_;
            hvv[mt][r] = fsigm(ao_[mt][r] + bo_) * fmaxf(c_, 0.f);
        }

    #pragma unroll
    for (int mt = 0; mt < 4; ++mt)
        #pragma unroll
        for (int r = 0; r < 4; ++r) {
            int row = mt * 16 + lk * 4 + r;
            Hs[row * HST + d0] = f2b(hvv[mt][r]);
            Cs[row * HST + d0] = f2b(cv[mt][r]);
        }
    __syncthreads();

    proj_rows(Hs, 64, pwl4, pbl, out, b * 64, tid);

    // wait for tb (block 0), then tree levels 1-2
    if (tid == 0) {
        while (atomicAdd(flag, 0) == 0) {}
        __threadfence();
    }
    __syncthreads();
    const float tbi = tb[d0], tbo = tb[128 + d0], tbu = tb[256 + d0];

    tree_level8<2>(BpkT, Hs, Cs, tbi, tbo, tbu, fb1, fb2, 32, 0, wv, l, lm, lk, d0);
    proj_rows(Hs, 32, pwl4, pbl, out, OFFL(1) + b * 32, tid);
    tree_level8<1>(BpkT, Hs, Cs, tbi, tbo, tbu, fb1, fb2, 16, 0, wv, l, lm, lk, d0);
    proj_rows(Hs, 16, pwl4, pbl, out, OFFL(2) + b * 16, tid);

    size_t gbase = (size_t)(OFFL(2) + b * 16) * 128;
    int e = tid * 8;
    if (e < 2048) {
        int row = e >> 7, d = e & 127;
        *(bf16x8*)(h_all + gbase + e) = *(const bf16x8*)&Hs[row * HST + d];
        *(bf16x8*)(c_all + gbase + e) = *(const bf16x8*)&Cs[row * HST + d];
    }
}

// ---------------------------------------------------------------------------
// K_tree4: 512t, FOUR tree levels per block from 64 staged rows of level Lin.
// ---------------------------------------------------------------------------
__global__ __launch_bounds__(512) void k_tree4(
    const bf16x8* __restrict__ BpkT, const float* __restrict__ tb,
    const float* __restrict__ Uf1_b, const float* __restrict__ Uf2_b,
    u16* __restrict__ h_all, u16* __restrict__ c_all,
    const float* __restrict__ proj_w, const float* __restrict__ proj_b,
    float* __restrict__ out, int Lin)
{
    __shared__ __align__(16) u16 HA[64 * HST];
    __shared__ __align__(16) u16 CA[64 * HST];
    __shared__ float pwl4[400];
    __shared__ float pbl[3];
    const int tid = threadIdx.x, bb = blockIdx.x;

    stage_pw(proj_w, proj_b, pwl4, pbl, tid, 512);

    const u16* hsrc = h_all + (size_t)(OFFL(Lin) + bb * 64) * 128;
    const u16* csrc = c_all + (size_t)(OFFL(Lin) + bb * 64) * 128;
    for (int e = tid * 8; e < 8192; e += 4096) {
        int row = e >> 7, d = e & 127;
        *(bf16x8*)&HA[row * HST + d] = *(const bf16x8*)(hsrc + e);
        *(bf16x8*)&CA[row * HST + d] = *(const bf16x8*)(csrc + e);
    }

    const int wv = tid >> 6, l = tid & 63;
    const int lm = l & 15, lk = l >> 4;
    const int d0 = wv * 16 + lm;
    const float tbi = tb[d0], tbo = tb[128 + d0], tbu = tb[256 + d0];
    const float fb1 = Uf1_b[d0], fb2 = Uf2_b[d0];
    __syncthreads();

    tree_level8<2>(BpkT, HA, CA, tbi, tbo, tbu, fb1, fb2, 32, 0, wv, l, lm, lk, d0);
    proj_rows(HA, 32, pwl4, pbl, out, OFFL(Lin + 1) + bb * 32, tid);
    tree_level8<1>(BpkT, HA, CA, tbi, tbo, tbu, fb1, fb2, 16, 0, wv, l, lm, lk, d0);
    proj_rows(HA, 16, pwl4, pbl, out, OFFL(Lin + 2) + bb * 16, tid);
    tree_level8<1>(BpkT, HA, CA, tbi, tbo, tbu, fb1, fb2, 8, 0, wv, l, lm, lk, d0);
    proj_rows(HA, 8, pwl4, pbl, out, OFFL(Lin + 3) + bb * 8, tid);
    tree_level8<1>(BpkT, HA, CA, tbi, tbo, tbu, fb1, fb2, 4, 0, wv, l, lm, lk, d0);
    proj_rows(HA, 4, pwl4, pbl, out, OFFL(Lin + 4) + bb * 4, tid);

    size_t gbase = (size_t)(OFFL(Lin + 4) + bb * 4) * 128;
    int e = tid * 8;
    if (e < 512) {
        int row = e >> 7, d = e & 127;
        *(bf16x8*)(h_all + gbase + e) = *(const bf16x8*)&HA[row * HST + d];
        *(bf16x8*)(c_all + gbase + e) = *(const bf16x8*)&CA[row * HST + d];
    }
}

// ---------------------------------------------------------------------------
// K_tail: ONE 512t block covering levels 11..17 from level 10 (128 rows).
// ---------------------------------------------------------------------------
__global__ __launch_bounds__(512) void k_tail(
    const bf16x8* __restrict__ BpkT, const float* __restrict__ tb,
    const float* __restrict__ Uf1_b, const float* __restrict__ Uf2_b,
    const u16* __restrict__ h_all, const u16* __restrict__ c_all,
    const float* __restrict__ proj_w, const float* __restrict__ proj_b,
    float* __restrict__ out)
{
    __shared__ __align__(16) u16 HA[128 * HST];   // 34,816 B
    __shared__ __align__(16) u16 CA[128 * HST];   // 34,816 B
    __shared__ float pwl4[400];
    __shared__ float pbl[3];
    const int tid = threadIdx.x;

    stage_pw(proj_w, proj_b, pwl4, pbl, tid, 512);

    const u16* hsrc = h_all + (size_t)OFFL(10) * 128;
    const u16* csrc = c_all + (size_t)OFFL(10) * 128;
    for (int e = tid * 8; e < 16384; e += 4096) {
        int row = e >> 7, d = e & 127;
        *(bf16x8*)&HA[row * HST + d] = *(const bf16x8*)(hsrc + e);
        *(bf16x8*)&CA[row * HST + d] = *(const bf16x8*)(csrc + e);
    }

    const int wv = tid >> 6, l = tid & 63;
    const int lm = l & 15, lk = l >> 4;
    const int d0 = wv * 16 + lm;
    const float tbi = tb[d0], tbo = tb[128 + d0], tbu = tb[256 + d0];
    const float fb1 = Uf1_b[d0], fb2 = Uf2_b[d0];
    __syncthreads();

    tree_level8<2>(BpkT, HA, CA, tbi, tbo, tbu, fb1, fb2, 64, 0,  wv, l, lm, lk, d0);
    tree_level8<2>(BpkT, HA, CA, tbi, tbo, tbu, fb1, fb2, 64, 32, wv, l, lm, lk, d0);
    proj_rows(HA, 64, pwl4, pbl, out, OFFL(11), tid);
    tree_level8<2>(BpkT, HA, CA, tbi, tbo, tbu, fb1, fb2, 32, 0, wv, l, lm, lk, d0);
    proj_rows(HA, 32, pwl4, pbl, out, OFFL(12), tid);
    tree_level8<1>(BpkT, HA, CA, tbi, tbo, tbu, fb1, fb2, 16, 0, wv, l, lm, lk, d0);
    proj_rows(HA, 16, pwl4, pbl, out, OFFL(13), tid);
    tree_level8<1>(BpkT, HA, CA, tbi, tbo, tbu, fb1, fb2, 8, 0, wv, l, lm, lk, d0);
    proj_rows(HA, 8, pwl4, pbl, out, OFFL(14), tid);
    tree_level8<1>(BpkT, HA, CA, tbi, tbo, tbu, fb1, fb2, 4, 0, wv, l, lm, lk, d0);
    proj_rows(HA, 4, pwl4, pbl, out, OFFL(15), tid);
    tree_level8<1>(BpkT, HA, CA, tbi, tbo, tbu, fb1, fb2, 2, 0, wv, l, lm, lk, d0);
    proj_rows(HA, 2, pwl4, pbl, out, OFFL(16), tid);
    tree_level8<1>(BpkT, HA, CA, tbi, tbo, tbu, fb1, fb2, 1, 0, wv, l, lm, lk, d0);
    proj_rows(HA, 1, pwl4, pbl, out, OFFL(17), tid);
}

// ---------------------------------------------------------------------------
extern "C" void kernel_launch(void* const* d_in, const int* in_sizes, int n_in,
                              void* d_out, int out_size, void* d_ws, size_t ws_size,
                              hipStream_t stream)
{
    const float* emb    = (const float*)d_in[0];
    const float* Wi_w   = (const float*)d_in[1];
    const float* Wi_b   = (const float*)d_in[2];
    const float* Wo_w   = (const float*)d_in[3];
    const float* Wo_b   = (const float*)d_in[4];
    const float* Wu_w   = (const float*)d_in[5];
    const float* Wu_b   = (const float*)d_in[6];
    const float* Ui_w   = (const float*)d_in[7];
    const float* Ui_b   = (const float*)d_in[8];
    const float* Uo_w   = (const float*)d_in[9];
    const float* Uo_b   = (const float*)d_in[10];
    const float* Uu_w   = (const float*)d_in[11];
    const float* Uu_b   = (const float*)d_in[12];
    const float* Uf1_w  = (const float*)d_in[13];
    const float* Uf1_b  = (const float*)d_in[14];
    const float* Uf2_w  = (const float*)d_in[15];
    const float* Uf2_b  = (const float*)d_in[16];
    const float* wih    = (const float*)d_in[17];
    const float* whh    = (const float*)d_in[18];
    const float* bih    = (const float*)d_in[19];
    const float* bhh    = (const float*)d_in[20];
    const float* proj_w = (const float*)d_in[21];
    const float* proj_b = (const float*)d_in[22];
    const int* toks     = (const int*)d_in[23];
    const int* tgts     = (const int*)d_in[24];

    char* ws = (char*)d_ws;
    u16*   h_all  = (u16*)(ws);                    // 67,108,864 B
    u16*   c_all  = (u16*)(ws + 67108864);         // 67,108,864 B
    u16*   BpkL   = (u16*)(ws + 134217728);        // 245,760 B
    u16*   BpkT   = (u16*)(ws + 134463488);        // 327,680 B
    float* xz     = (float*)(ws + 134791168);      // 102,400 B
    float* tb     = (float*)(ws + 134893568);      // 1,536 B
    int*   flag   = (int*)(ws + 134895104);        // 64 B
    u16*   emb_bf = (u16*)(ws + 134895168);        // 30,000,000 + slack B

    float* outp = (float*)d_out;

    hipMemsetAsync(flag, 0, 64, stream);
    k_pre<<<2022, 256, 0, stream>>>(Wi_w, Wo_w, Wu_w, Ui_w, Uo_w, Uu_w,
                                    Uf1_w, Uf2_w, emb, wih, bih, bhh, tgts,
                                    BpkL, BpkT, xz, emb_bf);
    k_fused<<<2049, 512, 0, stream>>>(emb_bf, toks, (const bf16x8*)BpkL,
                                      (const bf16x8*)BpkT,
                                      Wi_b, Wo_b, Wu_b, Uf1_b, Uf2_b,
                                      h_all, c_all, proj_w, proj_b, outp,
                                      whh, xz, Ui_w, Uo_w, Uu_w,
                                      Ui_b, Uo_b, Uu_b, tb, flag);
    // A: levels 3-6 from level 2 (32768 rows)
    k_tree4<<<512, 512, 0, stream>>>((const bf16x8*)BpkT, tb, Uf1_b, Uf2_b,
                                     h_all, c_all, proj_w, proj_b, outp, 2);
    // B: levels 7-10 from level 6 (2048 rows)
    k_tree4<<<32, 512, 0, stream>>>((const bf16x8*)BpkT, tb, Uf1_b, Uf2_b,
                                    h_all, c_all, proj_w, proj_b, outp, 6);
    // tail: levels 11-17 from level 10 (128 rows), one block
    k_tail<<<1, 512, 0, stream>>>((const bf16x8*)BpkT, tb, Uf1_b, Uf2_b,
                                  h_all, c_all, proj_w, proj_b, outp);
}

// Round 20
// 315.666 us; speedup vs baseline: 1.1333x; 1.1333x over previous
//
#include <hip/hip_runtime.h>
#include <hip/hip_bf16.h>
#include <math.h>

typedef unsigned short u16;
typedef unsigned int   u32;
typedef __attribute__((ext_vector_type(8))) short bf16x8;
typedef __attribute__((ext_vector_type(4))) float f32x4;

#define L_LEAF 131072
#define N_ALL  262143
#define HST 136   // h/c LDS row stride (elems): 128 + 8

// global row offset of tree level L (L=0 leaves): OFF = sum_{j<L} 131072>>j
#define OFFL(L) (262144 - (262144 >> (L)))

__device__ __forceinline__ float b2f(u16 u) {
    u32 x = ((u32)u) << 16;
    return __builtin_bit_cast(float, x);
}
__device__ __forceinline__ float lo2f(u32 p) { u32 x = p << 16;          return __builtin_bit_cast(float, x); }
__device__ __forceinline__ float hi2f(u32 p) { u32 x = p & 0xffff0000u;  return __builtin_bit_cast(float, x); }
__device__ __forceinline__ u16 f2b(float f) {
    u32 x = __builtin_bit_cast(u32, f);
    u32 r = x + 0x7fffu + ((x >> 16) & 1u);
    return (u16)(r >> 16);
}
__device__ __forceinline__ u32 pack2(float a, float b) {
    return (u32)f2b(a) | ((u32)f2b(b) << 16);
}
__device__ __forceinline__ float fsigm(float x) {
    return __builtin_amdgcn_rcpf(1.f + __builtin_amdgcn_exp2f(x * -1.44269504f));
}
__device__ __forceinline__ float ftanh(float x) {
    return 1.f - 2.f * __builtin_amdgcn_rcpf(__builtin_amdgcn_exp2f(x * 2.88539008f) + 1.f);
}

// ---------------------------------------------------------------------------
// proj of n_rows rows held in LDS Hrows[row*HST + d] -> out[grow0+row][3]
// ---------------------------------------------------------------------------
__device__ __forceinline__ void proj_rows(
    const u16* Hrows, int n_rows, const float* pwl4, const float* pbl,
    float* __restrict__ out, int grow0, int tid)
{
    int rp = tid >> 2, p = tid & 3;
    if (rp < n_rows) {
        float hv[32];
        #pragma unroll
        for (int c = 0; c < 4; ++c) {
            bf16x8 v = *(const bf16x8*)&Hrows[rp * HST + p * 32 + c * 8];
            #pragma unroll
            for (int e = 0; e < 8; ++e) hv[c * 8 + e] = b2f((u16)v[e]);
        }
        #pragma unroll
        for (int j = 0; j < 3; ++j) {
            float s = 0.f;
            #pragma unroll
            for (int e = 0; e < 32; ++e)
                s = fmaf(hv[e], pwl4[p * 100 + j * 32 + e], s);
            s += __shfl_xor(s, 1);
            s += __shfl_xor(s, 2);
            if (p == 0) out[(size_t)(grow0 + rp) * 3 + j] = s + pbl[j];
        }
    }
}

__device__ __forceinline__ void stage_pw(
    const float* __restrict__ proj_w, const float* __restrict__ proj_b,
    float* pwl4, float* pbl, int tid, int nthreads)
{
    for (int idx = tid; idx < 384; idx += nthreads) {
        int j = idx >> 7, d = idx & 127;
        int p = d >> 5, e = d & 31;
        pwl4[p * 100 + j * 32 + e] = proj_w[idx];
    }
    if (tid < 3) pbl[tid] = proj_b[tid];
}

// ---------------------------------------------------------------------------
// 512-thread (8-wave) tree level, SINGLE combined pass: wave wv owns 16 cols
// (d0 = wv*16+lm), one nt per gate (nt = gbase + wv).
// ---------------------------------------------------------------------------
template<int MTN>
__device__ __forceinline__ void tree_level8(
    const bf16x8* __restrict__ BpkT, u16* HA, u16* CA,
    float tbi, float tbo, float tbu, float fb1, float fb2,
    int n_out, int ro, int wv, int l, int lm, int lk, int d0)
{
    f32x4 ai[MTN], ao_[MTN], au[MTN], a1[MTN], a2[MTN];
    #pragma unroll
    for (int mt = 0; mt < MTN; ++mt) {
        ai[mt] = (f32x4){0.f, 0.f, 0.f, 0.f};
        ao_[mt] = ai[mt]; au[mt] = ai[mt]; a1[mt] = ai[mt]; a2[mt] = ai[mt];
    }
    #pragma unroll
    for (int kc = 0; kc < 8; ++kc) {
        int k0 = kc * 32 + lk * 8;
        bf16x8 a[MTN];
        #pragma unroll
        for (int mt = 0; mt < MTN; ++mt) {
            int rr = ro + mt * 16 + lm;
            const u16* src = (k0 < 128) ? &HA[(2 * rr) * HST + k0]
                                        : &HA[(2 * rr + 1) * HST + (k0 - 128)];
            a[mt] = *(const bf16x8*)src;
        }
        bf16x8 bi = BpkT[(kc * 40 + 0  + wv) * 64 + l];
        bf16x8 bo = BpkT[(kc * 40 + 8  + wv) * 64 + l];
        bf16x8 bu = BpkT[(kc * 40 + 16 + wv) * 64 + l];
        bf16x8 b1 = BpkT[(kc * 40 + 24 + wv) * 64 + l];
        bf16x8 b2 = BpkT[(kc * 40 + 32 + wv) * 64 + l];
        #pragma unroll
        for (int mt = 0; mt < MTN; ++mt) {
            ai[mt]  = __builtin_amdgcn_mfma_f32_16x16x32_bf16(a[mt], bi, ai[mt], 0, 0, 0);
            ao_[mt] = __builtin_amdgcn_mfma_f32_16x16x32_bf16(a[mt], bo, ao_[mt], 0, 0, 0);
            au[mt]  = __builtin_amdgcn_mfma_f32_16x16x32_bf16(a[mt], bu, au[mt], 0, 0, 0);
            a1[mt]  = __builtin_amdgcn_mfma_f32_16x16x32_bf16(a[mt], b1, a1[mt], 0, 0, 0);
            a2[mt]  = __builtin_amdgcn_mfma_f32_16x16x32_bf16(a[mt], b2, a2[mt], 0, 0, 0);
        }
    }

    float cv[MTN][4], hv[MTN][4];
    #pragma unroll
    for (int mt = 0; mt < MTN; ++mt)
        #pragma unroll
        for (int r = 0; r < 4; ++r) {
            int row = ro + mt * 16 + lk * 4 + r;
            float lc = b2f(CA[(2 * row) * HST + d0]);
            float rc = b2f(CA[(2 * row + 1) * HST + d0]);
            float ivv = fsigm(ai[mt][r] + tbi);
            float uv  = fmaxf(au[mt][r] + tbu, 0.f);
            float f1  = fsigm(a1[mt][r] + fb1);
            float f2  = fsigm(a2[mt][r] + fb2);
            float c_  = ivv * uv + f1 * lc + f2 * rc;
            cv[mt][r] = c_;
            hv[mt][r] = fsigm(ao_[mt][r] + tbo) * fmaxf(c_, 0.f);
        }

    __syncthreads();
    #pragma unroll
    for (int mt = 0; mt < MTN; ++mt)
        #pragma unroll
        for (int r = 0; r < 4; ++r) {
            int row = ro + mt * 16 + lk * 4 + r;
            if (row < n_out) {
                HA[row * HST + d0] = f2b(hv[mt][r]);
                CA[row * HST + d0] = f2b(cv[mt][r]);
            }
        }
    __syncthreads();
}

// ---------------------------------------------------------------------------
// K_pre (2023 blocks, 256t):
//  block 0: LSTM scan (spin-waits for xz blocks via cnt) + tb
//  blocks 1..50: xz rows; blocks 51..110: BpkL; 111..190: BpkT;
//  blocks 191..2022: emb f32->bf16.
// ---------------------------------------------------------------------------
__global__ __launch_bounds__(256) void k_pre(
    const float* __restrict__ Wi_w, const float* __restrict__ Wo_w,
    const float* __restrict__ Wu_w,
    const float* __restrict__ Ui_w, const float* __restrict__ Uo_w,
    const float* __restrict__ Uu_w, const float* __restrict__ Uf1_w,
    const float* __restrict__ Uf2_w,
    const float* __restrict__ emb, const float* __restrict__ wih,
    const float* __restrict__ bih, const float* __restrict__ bhh,
    const int* __restrict__ targets, const float* __restrict__ whh,
    const float* __restrict__ Ui_b, const float* __restrict__ Uo_b,
    const float* __restrict__ Uu_b,
    u16* __restrict__ BpkL, u16* __restrict__ BpkT, float* __restrict__ xz,
    u16* __restrict__ emb_bf, float* __restrict__ tb, int* __restrict__ cnt)
{
    __shared__ float te[300];
    const int b = blockIdx.x, tid = threadIdx.x;

    if (b == 0) {
        // ---------------- LSTM: K-split-4 GEMV scan + tb ----------------
        __shared__ float hbuf[128];
        __shared__ float zp[2048];
        const int q = tid & 3, rg = tid >> 2;

        u32 wreg[8][16];
        #pragma unroll
        for (int i = 0; i < 8; ++i) {
            const float* wr = whh + (size_t)(rg * 8 + i) * 128 + q * 32;
            #pragma unroll
            for (int k2 = 0; k2 < 16; ++k2)
                wreg[i][k2] = pack2(wr[2 * k2], wr[2 * k2 + 1]);
        }
        // wait for the 50 xz blocks
        if (tid == 0) {
            while (atomicAdd(cnt, 0) < 50) {}
            __threadfence();
        }
        __syncthreads();

        float c0 = 0.f;
        float nx0 = 0.f, nx1 = 0.f, nx2 = 0.f, nx3 = 0.f;
        if (tid < 128) {
            hbuf[tid] = 0.f;
            nx0 = xz[tid];       nx1 = xz[128 + tid];
            nx2 = xz[256 + tid]; nx3 = xz[384 + tid];
        }
        __syncthreads();

        for (int t = 0; t < 50; ++t) {
            float4 hv[8];
            #pragma unroll
            for (int m = 0; m < 8; ++m) hv[m] = ((const float4*)hbuf)[q * 8 + m];
            float za[8];
            #pragma unroll
            for (int i = 0; i < 8; ++i) {
                float a = 0.f;
                #pragma unroll
                for (int m = 0; m < 8; ++m) {
                    u32 w0 = wreg[i][2 * m], w1 = wreg[i][2 * m + 1];
                    a = fmaf(lo2f(w0), hv[m].x, a);
                    a = fmaf(hi2f(w0), hv[m].y, a);
                    a = fmaf(lo2f(w1), hv[m].z, a);
                    a = fmaf(hi2f(w1), hv[m].w, a);
                }
                za[i] = a;
            }
            float4* zdst = (float4*)(zp + q * 512 + rg * 8);
            zdst[0] = (float4){za[0], za[1], za[2], za[3]};
            zdst[1] = (float4){za[4], za[5], za[6], za[7]};
            __syncthreads();
            if (tid < 128) {
                int d = tid;
                float zi = zp[d]       + zp[512 + d]       + zp[1024 + d]       + zp[1536 + d]       + nx0;
                float zf = zp[128 + d] + zp[512 + 128 + d] + zp[1024 + 128 + d] + zp[1536 + 128 + d] + nx1;
                float zg = zp[256 + d] + zp[512 + 256 + d] + zp[1024 + 256 + d] + zp[1536 + 256 + d] + nx2;
                float zo = zp[384 + d] + zp[512 + 384 + d] + zp[1024 + 384 + d] + zp[1536 + 384 + d] + nx3;
                if (t < 49) {
                    const float* xn = xz + (t + 1) * 512;
                    nx0 = xn[d]; nx1 = xn[128 + d]; nx2 = xn[256 + d]; nx3 = xn[384 + d];
                }
                c0 = fsigm(zf) * c0 + fsigm(zi) * ftanh(zg);
                hbuf[d] = fsigm(zo) * ftanh(c0);
            }
            __syncthreads();
        }

        for (int rep = 0; rep < 2; ++rep) {
            int j = tid + rep * 256;
            if (j >= 384) break;
            int g = j >> 7, dd = j & 127;
            const float* W = (g == 0) ? Ui_w : (g == 1) ? Uo_w : Uu_w;
            const float* B = (g == 0) ? Ui_b : (g == 1) ? Uo_b : Uu_b;
            float acc = B[dd];
            for (int k = 0; k < 128; ++k)
                acc = fmaf(W[dd * 384 + 256 + k], hbuf[k], acc);
            tb[j] = acc;
        }
    } else if (b <= 50) {
        // ---------------- xz row t = b-1 ----------------
        int t = b - 1;
        int tgt = targets[t];
        if (tid < 75) {
            float4 v = *(const float4*)(emb + (size_t)tgt * 300 + tid * 4);
            te[tid * 4 + 0] = v.x; te[tid * 4 + 1] = v.y;
            te[tid * 4 + 2] = v.z; te[tid * 4 + 3] = v.w;
        }
        __syncthreads();
        for (int rep = 0; rep < 2; ++rep) {
            int j = tid + rep * 256;
            float acc = bih[j] + bhh[j];
            const float* wr = wih + (size_t)j * 300;
            for (int k4 = 0; k4 < 75; ++k4) {
                float4 wv = *(const float4*)(wr + k4 * 4);
                float4 tv = *(const float4*)&te[k4 * 4];
                acc = fmaf(wv.x, tv.x, acc);
                acc = fmaf(wv.y, tv.y, acc);
                acc = fmaf(wv.z, tv.z, acc);
                acc = fmaf(wv.w, tv.w, acc);
            }
            xz[t * 512 + j] = acc;
        }
        __threadfence();
        __syncthreads();
        if (tid == 0) atomicAdd(cnt, 1);
    } else if (b <= 110) {
        int gid = (b - 51) * 256 + tid;
        if (gid >= 15360) return;
        int l  = gid & 63;
        int nt = (gid >> 6) % 24;
        int kc = gid / (24 * 64);
        int n  = nt * 16 + (l & 15);
        int g  = n >> 7, d = n & 127;
        int k0 = kc * 32 + (l >> 4) * 8;
        const float* W = (g == 0) ? Wi_w : (g == 1) ? Wo_w : Wu_w;
        #pragma unroll
        for (int j = 0; j < 8; ++j) {
            int k = k0 + j;
            float v = (k < 300) ? W[d * 300 + k] : 0.f;
            BpkL[(size_t)gid * 8 + j] = f2b(v);
        }
    } else if (b <= 190) {
        int gid = (b - 111) * 256 + tid;
        if (gid >= 20480) return;
        int l  = gid & 63;
        int nt = (gid >> 6) % 40;
        int kc = gid / (40 * 64);
        int n  = nt * 16 + (l & 15);
        int g  = n >> 7, d = n & 127;
        int k0 = kc * 32 + (l >> 4) * 8;
        #pragma unroll
        for (int j = 0; j < 8; ++j) {
            int k = k0 + j;
            float v;
            if (g == 0)      v = Ui_w[d * 384 + k];
            else if (g == 1) v = Uo_w[d * 384 + k];
            else if (g == 2) v = Uu_w[d * 384 + k];
            else if (g == 3) v = (k < 128)  ? Uf1_w[d * 128 + k]       : 0.f;
            else             v = (k >= 128) ? Uf2_w[d * 128 + (k-128)] : 0.f;
            BpkT[(size_t)gid * 8 + j] = f2b(v);
        }
    } else {
        // emb f32 -> bf16: 3,750,000 float4 over blocks 191..2022 (1832).
        int base = (b - 191) * 2048;
        #pragma unroll
        for (int it = 0; it < 8; ++it) {
            int idx = base + it * 256 + tid;
            if (idx < 3750000) {
                float4 v = *(const float4*)(emb + (size_t)idx * 4);
                ushort4 o;
                o.x = f2b(v.x); o.y = f2b(v.y); o.z = f2b(v.z); o.w = f2b(v.w);
                *(ushort4*)(emb_bf + (size_t)idx * 4) = o;
            }
        }
    }
}

// ---------------------------------------------------------------------------
// K_fused: 512t / 8 waves, 64 leaf rows per block (2048). A direct from
// emb_bf; single combined-gate pass; levels 1-2 via tree_level8.
// ---------------------------------------------------------------------------
__global__ __launch_bounds__(512) void k_fused(
    const u16* __restrict__ emb_bf, const int* __restrict__ toks,
    const bf16x8* __restrict__ BpkL, const bf16x8* __restrict__ BpkT,
    const float* __restrict__ Wi_b, const float* __restrict__ Wo_b, const float* __restrict__ Wu_b,
    const float* __restrict__ tb,
    const float* __restrict__ Uf1_b, const float* __restrict__ Uf2_b,
    u16* __restrict__ h_all, u16* __restrict__ c_all,
    const float* __restrict__ proj_w, const float* __restrict__ proj_b,
    float* __restrict__ out)
{
    __shared__ __align__(16) u16 Hs[64 * HST];
    __shared__ __align__(16) u16 Cs[64 * HST];
    __shared__ float pwl4[400];
    __shared__ float pbl[3];
    const int tid = threadIdx.x, b = blockIdx.x;

    stage_pw(proj_w, proj_b, pwl4, pbl, tid, 512);

    const int wv = tid >> 6, l = tid & 63;
    const int lm = l & 15, lk = l >> 4;
    const int d0 = wv * 16 + lm;

    const float bi_ = Wi_b[d0], bo_ = Wo_b[d0], bu_ = Wu_b[d0];
    const float tbi = tb[d0], tbo = tb[128 + d0], tbu = tb[256 + d0];
    const float fb1 = Uf1_b[d0], fb2 = Uf2_b[d0];

    const u16* arow[4];
    #pragma unroll
    for (int mt = 0; mt < 4; ++mt) {
        int tok = toks[b * 64 + mt * 16 + lm];
        arow[mt] = emb_bf + (size_t)tok * 300 + lk * 8;
    }

    f32x4 ai[4], ao_[4], au[4];
    #pragma unroll
    for (int mt = 0; mt < 4; ++mt) {
        ai[mt] = (f32x4){0.f, 0.f, 0.f, 0.f};
        ao_[mt] = ai[mt]; au[mt] = ai[mt];
    }
    #pragma unroll
    for (int kc = 0; kc < 10; ++kc) {
        bf16x8 a[4];
        #pragma unroll
        for (int mt = 0; mt < 4; ++mt)
            a[mt] = *(const bf16x8*)(arow[mt] + kc * 32);
        bf16x8 bi = BpkL[(kc * 24 + 0  + wv) * 64 + l];
        bf16x8 bo = BpkL[(kc * 24 + 8  + wv) * 64 + l];
        bf16x8 bu = BpkL[(kc * 24 + 16 + wv) * 64 + l];
        #pragma unroll
        for (int mt = 0; mt < 4; ++mt) {
            ai[mt]  = __builtin_amdgcn_mfma_f32_16x16x32_bf16(a[mt], bi, ai[mt], 0, 0, 0);
            ao_[mt] = __builtin_amdgcn_mfma_f32_16x16x32_bf16(a[mt], bo, ao_[mt], 0, 0, 0);
            au[mt]  = __builtin_amdgcn_mfma_f32_16x16x32_bf16(a[mt], bu, au[mt], 0, 0, 0);
        }
    }

    float cv[4][4], hvv[4][4];
    #pragma unroll
    for (int mt = 0; mt < 4; ++mt)
        #pragma unroll
        for (int r = 0; r < 4; ++r) {
            float ivv = fsigm(ai[mt][r] + bi_);
            float uv  = fmaxf(au[mt][r] + bu_, 0.f);
            float c_  = ivv * uv;
            cv[mt][r] = c_;
            hvv[mt][r] = fsigm(ao_[mt][r] + bo_) * fmaxf(c_, 0.f);
        }

    #pragma unroll
    for (int mt = 0; mt < 4; ++mt)
        #pragma unroll
        for (int r = 0; r < 4; ++r) {
            int row = mt * 16 + lk * 4 + r;
            Hs[row * HST + d0] = f2b(hvv[mt][r]);
            Cs[row * HST + d0] = f2b(cv[mt][r]);
        }
    __syncthreads();

    proj_rows(Hs, 64, pwl4, pbl, out, b * 64, tid);

    tree_level8<2>(BpkT, Hs, Cs, tbi, tbo, tbu, fb1, fb2, 32, 0, wv, l, lm, lk, d0);
    proj_rows(Hs, 32, pwl4, pbl, out, OFFL(1) + b * 32, tid);
    tree_level8<1>(BpkT, Hs, Cs, tbi, tbo, tbu, fb1, fb2, 16, 0, wv, l, lm, lk, d0);
    proj_rows(Hs, 16, pwl4, pbl, out, OFFL(2) + b * 16, tid);

    size_t gbase = (size_t)(OFFL(2) + b * 16) * 128;
    int e = tid * 8;
    if (e < 2048) {
        int row = e >> 7, d = e & 127;
        *(bf16x8*)(h_all + gbase + e) = *(const bf16x8*)&Hs[row * HST + d];
        *(bf16x8*)(c_all + gbase + e) = *(const bf16x8*)&Cs[row * HST + d];
    }
}

// ---------------------------------------------------------------------------
// K_tree4: 512t, FOUR tree levels per block from 64 staged rows of level Lin.
// Single-pass tree_level8 per level.
// ---------------------------------------------------------------------------
__global__ __launch_bounds__(512) void k_tree4(
    const bf16x8* __restrict__ BpkT, const float* __restrict__ tb,
    const float* __restrict__ Uf1_b, const float* __restrict__ Uf2_b,
    u16* __restrict__ h_all, u16* __restrict__ c_all,
    const float* __restrict__ proj_w, const float* __restrict__ proj_b,
    float* __restrict__ out, int Lin)
{
    __shared__ __align__(16) u16 HA[64 * HST];
    __shared__ __align__(16) u16 CA[64 * HST];
    __shared__ float pwl4[400];
    __shared__ float pbl[3];
    const int tid = threadIdx.x, bb = blockIdx.x;

    stage_pw(proj_w, proj_b, pwl4, pbl, tid, 512);

    const u16* hsrc = h_all + (size_t)(OFFL(Lin) + bb * 64) * 128;
    const u16* csrc = c_all + (size_t)(OFFL(Lin) + bb * 64) * 128;
    for (int e = tid * 8; e < 8192; e += 4096) {
        int row = e >> 7, d = e & 127;
        *(bf16x8*)&HA[row * HST + d] = *(const bf16x8*)(hsrc + e);
        *(bf16x8*)&CA[row * HST + d] = *(const bf16x8*)(csrc + e);
    }

    const int wv = tid >> 6, l = tid & 63;
    const int lm = l & 15, lk = l >> 4;
    const int d0 = wv * 16 + lm;
    const float tbi = tb[d0], tbo = tb[128 + d0], tbu = tb[256 + d0];
    const float fb1 = Uf1_b[d0], fb2 = Uf2_b[d0];
    __syncthreads();

    tree_level8<2>(BpkT, HA, CA, tbi, tbo, tbu, fb1, fb2, 32, 0, wv, l, lm, lk, d0);
    proj_rows(HA, 32, pwl4, pbl, out, OFFL(Lin + 1) + bb * 32, tid);
    tree_level8<1>(BpkT, HA, CA, tbi, tbo, tbu, fb1, fb2, 16, 0, wv, l, lm, lk, d0);
    proj_rows(HA, 16, pwl4, pbl, out, OFFL(Lin + 2) + bb * 16, tid);
    tree_level8<1>(BpkT, HA, CA, tbi, tbo, tbu, fb1, fb2, 8, 0, wv, l, lm, lk, d0);
    proj_rows(HA, 8, pwl4, pbl, out, OFFL(Lin + 3) + bb * 8, tid);
    tree_level8<1>(BpkT, HA, CA, tbi, tbo, tbu, fb1, fb2, 4, 0, wv, l, lm, lk, d0);
    proj_rows(HA, 4, pwl4, pbl, out, OFFL(Lin + 4) + bb * 4, tid);

    size_t gbase = (size_t)(OFFL(Lin + 4) + bb * 4) * 128;
    int e = tid * 8;
    if (e < 512) {
        int row = e >> 7, d = e & 127;
        *(bf16x8*)(h_all + gbase + e) = *(const bf16x8*)&HA[row * HST + d];
        *(bf16x8*)(c_all + gbase + e) = *(const bf16x8*)&CA[row * HST + d];
    }
}

// ---------------------------------------------------------------------------
// K_tail: ONE 512t block covering levels 11..17 from level 10 (128 rows).
// ---------------------------------------------------------------------------
__global__ __launch_bounds__(512) void k_tail(
    const bf16x8* __restrict__ BpkT, const float* __restrict__ tb,
    const float* __restrict__ Uf1_b, const float* __restrict__ Uf2_b,
    const u16* __restrict__ h_all, const u16* __restrict__ c_all,
    const float* __restrict__ proj_w, const float* __restrict__ proj_b,
    float* __restrict__ out)
{
    __shared__ __align__(16) u16 HA[128 * HST];   // 34,816 B
    __shared__ __align__(16) u16 CA[128 * HST];   // 34,816 B
    __shared__ float pwl4[400];
    __shared__ float pbl[3];
    const int tid = threadIdx.x;

    stage_pw(proj_w, proj_b, pwl4, pbl, tid, 512);

    const u16* hsrc = h_all + (size_t)OFFL(10) * 128;
    const u16* csrc = c_all + (size_t)OFFL(10) * 128;
    for (int e = tid * 8; e < 16384; e += 4096) {
        int row = e >> 7, d = e & 127;
        *(bf16x8*)&HA[row * HST + d] = *(const bf16x8*)(hsrc + e);
        *(bf16x8*)&CA[row * HST + d] = *(const bf16x8*)(csrc + e);
    }

    const int wv = tid >> 6, l = tid & 63;
    const int lm = l & 15, lk = l >> 4;
    const int d0 = wv * 16 + lm;
    const float tbi = tb[d0], tbo = tb[128 + d0], tbu = tb[256 + d0];
    const float fb1 = Uf1_b[d0], fb2 = Uf2_b[d0];
    __syncthreads();

    // level 11: 64 out rows, two MTN=2 chunks
    tree_level8<2>(BpkT, HA, CA, tbi, tbo, tbu, fb1, fb2, 64, 0,  wv, l, lm, lk, d0);
    tree_level8<2>(BpkT, HA, CA, tbi, tbo, tbu, fb1, fb2, 64, 32, wv, l, lm, lk, d0);
    proj_rows(HA, 64, pwl4, pbl, out, OFFL(11), tid);
    tree_level8<2>(BpkT, HA, CA, tbi, tbo, tbu, fb1, fb2, 32, 0, wv, l, lm, lk, d0);
    proj_rows(HA, 32, pwl4, pbl, out, OFFL(12), tid);
    tree_level8<1>(BpkT, HA, CA, tbi, tbo, tbu, fb1, fb2, 16, 0, wv, l, lm, lk, d0);
    proj_rows(HA, 16, pwl4, pbl, out, OFFL(13), tid);
    tree_level8<1>(BpkT, HA, CA, tbi, tbo, tbu, fb1, fb2, 8, 0, wv, l, lm, lk, d0);
    proj_rows(HA, 8, pwl4, pbl, out, OFFL(14), tid);
    tree_level8<1>(BpkT, HA, CA, tbi, tbo, tbu, fb1, fb2, 4, 0, wv, l, lm, lk, d0);
    proj_rows(HA, 4, pwl4, pbl, out, OFFL(15), tid);
    tree_level8<1>(BpkT, HA, CA, tbi, tbo, tbu, fb1, fb2, 2, 0, wv, l, lm, lk, d0);
    proj_rows(HA, 2, pwl4, pbl, out, OFFL(16), tid);
    tree_level8<1>(BpkT, HA, CA, tbi, tbo, tbu, fb1, fb2, 1, 0, wv, l, lm, lk, d0);
    proj_rows(HA, 1, pwl4, pbl, out, OFFL(17), tid);
}

// ---------------------------------------------------------------------------
extern "C" void kernel_launch(void* const* d_in, const int* in_sizes, int n_in,
                              void* d_out, int out_size, void* d_ws, size_t ws_size,
                              hipStream_t stream)
{
    const float* emb    = (const float*)d_in[0];
    const float* Wi_w   = (const float*)d_in[1];
    const float* Wi_b   = (const float*)d_in[2];
    const float* Wo_w   = (const float*)d_in[3];
    const float* Wo_b   = (const float*)d_in[4];
    const float* Wu_w   = (const float*)d_in[5];
    const float* Wu_b   = (const float*)d_in[6];
    const float* Ui_w   = (const float*)d_in[7];
    const float* Ui_b   = (const float*)d_in[8];
    const float* Uo_w   = (const float*)d_in[9];
    const float* Uo_b   = (const float*)d_in[10];
    const float* Uu_w   = (const float*)d_in[11];
    const float* Uu_b   = (const float*)d_in[12];
    const float* Uf1_w  = (const float*)d_in[13];
    const float* Uf1_b  = (const float*)d_in[14];
    const float* Uf2_w  = (const float*)d_in[15];
    const float* Uf2_b  = (const float*)d_in[16];
    const float* wih    = (const float*)d_in[17];
    const float* whh    = (const float*)d_in[18];
    const float* bih    = (const float*)d_in[19];
    const float* bhh    = (const float*)d_in[20];
    const float* proj_w = (const float*)d_in[21];
    const float* proj_b = (const float*)d_in[22];
    const int* toks     = (const int*)d_in[23];
    const int* tgts     = (const int*)d_in[24];

    char* ws = (char*)d_ws;
    u16*   h_all  = (u16*)(ws);                    // 67,108,864 B
    u16*   c_all  = (u16*)(ws + 67108864);         // 67,108,864 B
    u16*   BpkL   = (u16*)(ws + 134217728);        // 245,760 B
    u16*   BpkT   = (u16*)(ws + 134463488);        // 327,680 B
    float* xz     = (float*)(ws + 134791168);      // 102,400 B
    float* tb     = (float*)(ws + 134893568);      // 1,536 B
    int*   cnt    = (int*)(ws + 134895104);        // 64 B
    u16*   emb_bf = (u16*)(ws + 134895168);        // 30,000,000 + slack B

    float* outp = (float*)d_out;

    hipMemsetAsync(cnt, 0, 64, stream);
    k_pre<<<2023, 256, 0, stream>>>(Wi_w, Wo_w, Wu_w, Ui_w, Uo_w, Uu_w,
                                    Uf1_w, Uf2_w, emb, wih, bih, bhh, tgts,
                                    whh, Ui_b, Uo_b, Uu_b,
                                    BpkL, BpkT, xz, emb_bf, tb, cnt);
    k_fused<<<2048, 512, 0, stream>>>(emb_bf, toks, (const bf16x8*)BpkL,
                                      (const bf16x8*)BpkT,
                                      Wi_b, Wo_b, Wu_b, tb, Uf1_b, Uf2_b,
                                      h_all, c_all, proj_w, proj_b, outp);
    // A: levels 3-6 from level 2 (32768 rows)
    k_tree4<<<512, 512, 0, stream>>>((const bf16x8*)BpkT, tb, Uf1_b, Uf2_b,
                                     h_all, c_all, proj_w, proj_b, outp, 2);
    // B: levels 7-10 from level 6 (2048 rows)
    k_tree4<<<32, 512, 0, stream>>>((const bf16x8*)BpkT, tb, Uf1_b, Uf2_b,
                                    h_all, c_all, proj_w, proj_b, outp, 6);
    // tail: levels 11-17 from level 10 (128 rows), one block
    k_tail<<<1, 512, 0, stream>>>((const bf16x8*)BpkT, tb, Uf1_b, Uf2_b,
                                  h_all, c_all, proj_w, proj_b, outp);
}